// Round 5
// baseline (2200.806 us; speedup 1.0000x reference)
//
#include <hip/hip_runtime.h>

#define N_NODES 165888
#define N_EDGES 3317760
#define NBKT 648          // N_NODES >> 8
#define LN_EPS 1e-5f

typedef _Float16 f16;
typedef _Float16 half8 __attribute__((ext_vector_type(8)));
typedef float f32x4 __attribute__((ext_vector_type(4)));

__device__ __forceinline__ f32x4 mfma16(half8 a, half8 b, f32x4 c) {
    return __builtin_amdgcn_mfma_f32_16x16x32_f16(a, b, c, 0, 0, 0);
}

// ---------------- CSR build: 2-pass bucket partition ----------------

// A1: histogram of dst>>8 into 648 counters
__global__ void k_bhist(const int* __restrict__ dst, int* __restrict__ bcnt) {
    int stride = gridDim.x * blockDim.x;
    for (int e = blockIdx.x * blockDim.x + threadIdx.x; e < N_EDGES; e += stride)
        atomicAdd(&bcnt[dst[e] >> 8], 1);
}

// A2: scan 648 counters -> bbase (exclusive), init bcur, terminators
__global__ void k_bscan(const int* __restrict__ bcnt, int* __restrict__ bbase,
                        int* __restrict__ bcur, int* __restrict__ roff) {
    __shared__ int s[1024];
    int t = threadIdx.x;
    int v = (t < NBKT) ? bcnt[t] : 0;
    s[t] = v;
    __syncthreads();
    for (int off = 1; off < 1024; off <<= 1) {
        int u = (t >= off) ? s[t - off] : 0;
        __syncthreads();
        s[t] += u;
        __syncthreads();
    }
    if (t < NBKT) {
        int base = s[t] - v;       // exclusive
        bbase[t] = base;
        bcur[t] = base;
    }
    if (t == 0) {
        bbase[NBKT] = N_EDGES;
        roff[N_NODES] = N_EDGES;
    }
}

// A3: scatter packed (dlow<<24 | src) into bucket regions
__global__ void k_bscatter(const int* __restrict__ src, const int* __restrict__ dst,
                           int* __restrict__ bcur, unsigned* __restrict__ pairs) {
    int stride = gridDim.x * blockDim.x;
    for (int e = blockIdx.x * blockDim.x + threadIdx.x; e < N_EDGES; e += stride) {
        int d = dst[e];
        int pos = atomicAdd(&bcur[d >> 8], 1);
        pairs[pos] = ((unsigned)(d & 255) << 24) | (unsigned)src[e];
    }
}

// B: per bucket -> node-exact csr + roff (all traffic within 20KB L2-hot window)
__global__ __launch_bounds__(256) void k_csr(const unsigned* __restrict__ pairs,
                                             const int* __restrict__ bbase,
                                             int* __restrict__ roff,
                                             int* __restrict__ csr) {
    __shared__ int hist[256];
    __shared__ int sc[256];
    __shared__ int curs[256];
    int b = blockIdx.x;
    int e0 = bbase[b], e1 = bbase[b + 1];
    int t = threadIdx.x;
    hist[t] = 0;
    __syncthreads();
    for (int p = e0 + t; p < e1; p += 256)
        atomicAdd(&hist[pairs[p] >> 24], 1);
    __syncthreads();
    int own = hist[t];
    sc[t] = own;
    __syncthreads();
    for (int off = 1; off < 256; off <<= 1) {
        int u = (t >= off) ? sc[t - off] : 0;
        __syncthreads();
        sc[t] += u;
        __syncthreads();
    }
    int base = e0 + sc[t] - own;   // exclusive within bucket, global offset
    roff[(b << 8) + t] = base;
    curs[t] = base;
    __syncthreads();
    for (int p = e0 + t; p < e1; p += 256) {
        unsigned pk = pairs[p];
        int pos = atomicAdd(&curs[pk >> 24], 1);
        csr[pos] = (int)(pk & 0xFFFFFF);
    }
}

// ---------------- weight conversion to fp16 ----------------

__global__ void k_wcvt(const float* __restrict__ Wroot, const float* __restrict__ Wrel,
                       const float* __restrict__ Wres, const float* __restrict__ Win,
                       f16* __restrict__ W2h, f16* __restrict__ Wresh, f16* __restrict__ Winh) {
    int i = blockIdx.x * 256 + threadIdx.x;
    if (i < 4 * 64 * 128) {
        int l = i >> 13, r = i & 8191, j = r >> 7, k = r & 127;
        float v = (k < 64) ? Wroot[l * 4096 + j * 64 + k] : Wrel[l * 4096 + j * 64 + k - 64];
        W2h[i] = (f16)v;
    } else if (i < 4 * 64 * 128 + 4096) {
        int t = i - 4 * 64 * 128;
        Wresh[t] = (f16)Wres[t];
    } else if (i < 4 * 64 * 128 + 4096 + 2048) {
        int t = i - (4 * 64 * 128 + 4096);
        int j = t >> 5, k = t & 31;
        Winh[t] = (k < 9) ? (f16)Win[j * 9 + k] : (f16)0.f;
    }
}

// ---------------- input projection + residual via MFMA ----------------

__global__ __launch_bounds__(256) void k_proj(
        const float* __restrict__ x, const f16* __restrict__ Winh,
        const float* __restrict__ bin, const f16* __restrict__ Wresh,
        const float* __restrict__ bres, f16* __restrict__ h0,
        f16* __restrict__ res) {
    __shared__ f16 hs[4][16][64];
    int tid = threadIdx.x, w = tid >> 6, lane = tid & 63, li = lane & 15, kg = lane >> 4;
    int nb = blockIdx.x * 64 + w * 16;
    int node = nb + li;

    half8 ax;
    #pragma unroll
    for (int e = 0; e < 8; ++e) ax[e] = (f16)0.f;
    if (kg == 0) {
        #pragma unroll
        for (int e = 0; e < 8; ++e) ax[e] = (f16)x[(size_t)node * 9 + e];
    } else if (kg == 1) {
        ax[0] = (f16)x[(size_t)node * 9 + 8];
    }

    f32x4 ch[4];
    #pragma unroll
    for (int jt = 0; jt < 4; ++jt) {
        half8 b = *(const half8*)(Winh + (jt * 16 + li) * 32 + kg * 8);
        f32x4 z = {0.f, 0.f, 0.f, 0.f};
        ch[jt] = mfma16(ax, b, z);
    }
    #pragma unroll
    for (int jt = 0; jt < 4; ++jt) {
        float bb = bin[jt * 16 + li];
        #pragma unroll
        for (int r = 0; r < 4; ++r) {
            int row = kg * 4 + r;
            float v = ch[jt][r] + bb;
            f16 hv = (f16)v;
            h0[(size_t)(nb + row) * 64 + jt * 16 + li] = hv;
            int col = jt * 16 + li;
            hs[w][row][col ^ ((row & 7) * 8)] = hv;   // XOR-swizzle
        }
    }
    __syncthreads();

    f32x4 cr[4];
    #pragma unroll
    for (int jt = 0; jt < 4; ++jt) { f32x4 z = {0.f,0.f,0.f,0.f}; cr[jt] = z; }
    #pragma unroll
    for (int s = 0; s < 2; ++s) {
        int k0 = s * 32 + kg * 8;
        half8 a = *(const half8*)(&hs[w][li][k0 ^ ((li & 7) * 8)]);
        #pragma unroll
        for (int jt = 0; jt < 4; ++jt) {
            half8 b = *(const half8*)(Wresh + (jt * 16 + li) * 64 + k0);
            cr[jt] = mfma16(a, b, cr[jt]);
        }
    }
    #pragma unroll
    for (int jt = 0; jt < 4; ++jt) {
        float bb = bres[jt * 16 + li];
        #pragma unroll
        for (int r = 0; r < 4; ++r)
            res[(size_t)(nb + kg * 4 + r) * 64 + jt * 16 + li] = (f16)(cr[jt][r] + bb);
    }
}

// ---------------- gather: wave per node, direct csr loads ----------------

__global__ __launch_bounds__(256) void k_gather(
        const f16* __restrict__ h, const int* __restrict__ roff,
        const int* __restrict__ csr, f16* __restrict__ agg) {
    int lane = threadIdx.x & 63;
    int gwave = (blockIdx.x * blockDim.x + threadIdx.x) >> 6;
    int nw = (gridDim.x * blockDim.x) >> 6;
    int g = lane >> 3, s = lane & 7;
    for (int n = gwave; n < N_NODES; n += nw) {
        int e0 = roff[n], e1 = roff[n + 1];
        float a0 = 0, a1 = 0, a2 = 0, a3 = 0, a4 = 0, a5 = 0, a6 = 0, a7 = 0;
        int p = e0 + g;
        for (; p + 8 < e1; p += 16) {
            int i0 = csr[p];
            int i1 = csr[p + 8];
            half8 v0 = *(const half8*)(h + ((size_t)i0 << 6) + s * 8);
            half8 v1 = *(const half8*)(h + ((size_t)i1 << 6) + s * 8);
            a0 += (float)v0[0] + (float)v1[0];
            a1 += (float)v0[1] + (float)v1[1];
            a2 += (float)v0[2] + (float)v1[2];
            a3 += (float)v0[3] + (float)v1[3];
            a4 += (float)v0[4] + (float)v1[4];
            a5 += (float)v0[5] + (float)v1[5];
            a6 += (float)v0[6] + (float)v1[6];
            a7 += (float)v0[7] + (float)v1[7];
        }
        if (p < e1) {
            int i0 = csr[p];
            half8 v0 = *(const half8*)(h + ((size_t)i0 << 6) + s * 8);
            a0 += (float)v0[0]; a1 += (float)v0[1];
            a2 += (float)v0[2]; a3 += (float)v0[3];
            a4 += (float)v0[4]; a5 += (float)v0[5];
            a6 += (float)v0[6]; a7 += (float)v0[7];
        }
        #pragma unroll
        for (int off = 8; off <= 32; off <<= 1) {
            a0 += __shfl_xor(a0, off, 64);
            a1 += __shfl_xor(a1, off, 64);
            a2 += __shfl_xor(a2, off, 64);
            a3 += __shfl_xor(a3, off, 64);
            a4 += __shfl_xor(a4, off, 64);
            a5 += __shfl_xor(a5, off, 64);
            a6 += __shfl_xor(a6, off, 64);
            a7 += __shfl_xor(a7, off, 64);
        }
        if (lane < 8) {
            half8 o;
            o[0] = (f16)a0; o[1] = (f16)a1; o[2] = (f16)a2; o[3] = (f16)a3;
            o[4] = (f16)a4; o[5] = (f16)a5; o[6] = (f16)a6; o[7] = (f16)a7;
            *(half8*)(agg + ((size_t)n << 6) + s * 8) = o;
        }
    }
}

// ---------------- fused update: MFMA matvec + LN + leaky + residual ----------------

__global__ __launch_bounds__(256) void k_update(
        const f16* __restrict__ h, const f16* __restrict__ agg,
        const f16* __restrict__ res, const f16* __restrict__ W2h,
        const float* __restrict__ bconv, const float* __restrict__ lng,
        const float* __restrict__ lnb, f16* __restrict__ hn) {
    int tid = threadIdx.x, w = tid >> 6, lane = tid & 63, li = lane & 15, kg = lane >> 4;
    int nb = blockIdx.x * 64 + w * 16;
    int node = nb + li;

    f32x4 acc[4];
    #pragma unroll
    for (int jt = 0; jt < 4; ++jt) { f32x4 z = {0.f,0.f,0.f,0.f}; acc[jt] = z; }

    #pragma unroll
    for (int s = 0; s < 4; ++s) {
        half8 a = (s < 2)
            ? *(const half8*)(h   + ((size_t)node << 6) + s * 32 + kg * 8)
            : *(const half8*)(agg + ((size_t)node << 6) + (s - 2) * 32 + kg * 8);
        #pragma unroll
        for (int jt = 0; jt < 4; ++jt) {
            half8 b = *(const half8*)(W2h + (size_t)(jt * 16 + li) * 128 + s * 32 + kg * 8);
            acc[jt] = mfma16(a, b, acc[jt]);
        }
    }

    #pragma unroll
    for (int jt = 0; jt < 4; ++jt) {
        float bb = bconv[jt * 16 + li];
        #pragma unroll
        for (int r = 0; r < 4; ++r) acc[jt][r] += bb;
    }

    float mu[4], rstd[4];
    #pragma unroll
    for (int r = 0; r < 4; ++r) {
        float v = acc[0][r] + acc[1][r] + acc[2][r] + acc[3][r];
        v += __shfl_xor(v, 1, 64); v += __shfl_xor(v, 2, 64);
        v += __shfl_xor(v, 4, 64); v += __shfl_xor(v, 8, 64);
        mu[r] = v * (1.f / 64.f);
    }
    #pragma unroll
    for (int r = 0; r < 4; ++r) {
        float d0 = acc[0][r] - mu[r], d1 = acc[1][r] - mu[r];
        float d2 = acc[2][r] - mu[r], d3 = acc[3][r] - mu[r];
        float vv = d0 * d0 + d1 * d1 + d2 * d2 + d3 * d3;
        vv += __shfl_xor(vv, 1, 64); vv += __shfl_xor(vv, 2, 64);
        vv += __shfl_xor(vv, 4, 64); vv += __shfl_xor(vv, 8, 64);
        rstd[r] = rsqrtf(vv * (1.f / 64.f) + LN_EPS);
    }
    #pragma unroll
    for (int jt = 0; jt < 4; ++jt) {
        float gg = lng[jt * 16 + li], bb = lnb[jt * 16 + li];
        #pragma unroll
        for (int r = 0; r < 4; ++r) {
            float y = (acc[jt][r] - mu[r]) * rstd[r] * gg + bb;
            y = (y > 0.f) ? y : 0.01f * y;
            y += (float)res[(size_t)(nb + kg * 4 + r) * 64 + jt * 16 + li];
            hn[(size_t)(nb + kg * 4 + r) * 64 + jt * 16 + li] = (f16)y;
        }
    }
}

// ---------------- output projection: node per lane ----------------

__global__ __launch_bounds__(256) void k_out(
        const f16* __restrict__ h, const float* __restrict__ Wout,
        const float* __restrict__ bout, float* __restrict__ out) {
    int node = blockIdx.x * 256 + threadIdx.x;
    float acc[9];
    #pragma unroll
    for (int c = 0; c < 9; ++c) acc[c] = bout[c];
    #pragma unroll
    for (int cc = 0; cc < 8; ++cc) {
        half8 v = *(const half8*)(h + ((size_t)node << 6) + cc * 8);
        float f[8];
        #pragma unroll
        for (int e = 0; e < 8; ++e) f[e] = (float)v[e];
        #pragma unroll
        for (int c = 0; c < 9; ++c) {
            #pragma unroll
            for (int e = 0; e < 8; ++e)
                acc[c] += f[e] * Wout[c * 64 + cc * 8 + e];
        }
    }
    #pragma unroll
    for (int c = 0; c < 9; ++c) out[(size_t)node * 9 + c] = acc[c];
}

extern "C" void kernel_launch(void* const* d_in, const int* in_sizes, int n_in,
                              void* d_out, int out_size, void* d_ws, size_t ws_size,
                              hipStream_t stream) {
    const float* x     = (const float*)d_in[0];
    const int*   ei    = (const int*)d_in[1];
    const float* Win   = (const float*)d_in[2];
    const float* bin   = (const float*)d_in[3];
    const float* Wrel  = (const float*)d_in[4];
    const float* Wroot = (const float*)d_in[5];
    const float* bconv = (const float*)d_in[6];
    const float* Wres  = (const float*)d_in[7];
    const float* bres  = (const float*)d_in[8];
    const float* lng   = (const float*)d_in[9];
    const float* lnb   = (const float*)d_in[10];
    const float* Wout  = (const float*)d_in[11];
    const float* bout  = (const float*)d_in[12];
    float* out = (float*)d_out;

    char* p = (char*)d_ws;
    auto alloc = [&](size_t bytes) {
        char* r = p;
        p += (bytes + 255) & ~(size_t)255;
        return r;
    };
    f16*      h0    = (f16*)alloc((size_t)N_NODES * 64 * 2);
    f16*      h1    = (f16*)alloc((size_t)N_NODES * 64 * 2);
    f16*      res   = (f16*)alloc((size_t)N_NODES * 64 * 2);
    f16*      agg   = (f16*)alloc((size_t)N_NODES * 64 * 2);
    int*      csr   = (int*)alloc((size_t)N_EDGES * 4);
    unsigned* pairs = (unsigned*)alloc((size_t)N_EDGES * 4);
    int*      roff  = (int*)alloc((size_t)(N_NODES + 1) * 4);
    int*      bcnt  = (int*)alloc((NBKT + 1) * 4);
    int*      bbase = (int*)alloc((NBKT + 1) * 4);
    int*      bcur  = (int*)alloc((NBKT + 1) * 4);
    f16*      W2h   = (f16*)alloc(4 * 64 * 128 * 2);
    f16*      Wresh = (f16*)alloc(64 * 64 * 2);
    f16*      Winh  = (f16*)alloc(64 * 32 * 2);

    const int* srcv = ei;
    const int* dstv = ei + N_EDGES;

    hipMemsetAsync(bcnt, 0, (NBKT + 1) * 4, stream);
    k_bhist<<<2048, 256, 0, stream>>>(dstv, bcnt);
    k_bscan<<<1, 1024, 0, stream>>>(bcnt, bbase, bcur, roff);
    k_bscatter<<<2048, 256, 0, stream>>>(srcv, dstv, bcur, pairs);
    k_csr<<<NBKT, 256, 0, stream>>>(pairs, bbase, roff, csr);

    k_wcvt<<<152, 256, 0, stream>>>(Wroot, Wrel, Wres, Win, W2h, Wresh, Winh);
    k_proj<<<N_NODES / 64, 256, 0, stream>>>(x, Winh, bin, Wresh, bres, h0, res);

    f16* ha = h0;
    f16* hb = h1;
    for (int l = 0; l < 4; ++l) {
        k_gather<<<4096, 256, 0, stream>>>(ha, roff, csr, agg);
        k_update<<<N_NODES / 64, 256, 0, stream>>>(ha, agg, res, W2h + (size_t)l * 64 * 128,
                                                   bconv + l * 64, lng, lnb, hb);
        f16* t = ha; ha = hb; hb = t;
    }
    k_out<<<N_NODES / 256, 256, 0, stream>>>(ha, Wout, bout, out);
}